// Round 1
// baseline (1735.951 us; speedup 1.0000x reference)
//
#include <hip/hip_runtime.h>
#include <math.h>

typedef __attribute__((ext_vector_type(8))) short bf16x8;
typedef __attribute__((ext_vector_type(4))) float f32x4;
typedef unsigned short u16;
typedef unsigned int u32;

#define DEV static __device__ __forceinline__

DEV u16 f2bf(float f){
  u32 u = __builtin_bit_cast(u32, f);
  u32 r = (u + 0x7fffu + ((u >> 16) & 1u)) >> 16;
  return (u16)r;
}
DEV float bf2f(u16 h){
  u32 u = ((u32)h) << 16;
  return __builtin_bit_cast(float, u);
}
DEV float gelu_exact(float x){ return 0.5f*x*(1.f+erff(x*0.70710678118654752f)); }

// ---------------- elementwise ----------------
__global__ __launch_bounds__(256) void k_copy_f32(const float* __restrict__ in, float* __restrict__ out, int n4){
  int i = blockIdx.x*256 + threadIdx.x;
  if (i < n4) ((float4*)out)[i] = ((const float4*)in)[i];
}

__global__ __launch_bounds__(256) void k_cvt_bf16(const float* __restrict__ in, u16* __restrict__ out, int n4){
  int i = blockIdx.x*256 + threadIdx.x;
  if (i < n4){
    float4 v = ((const float4*)in)[i];
    ushort4 o;
    o.x = f2bf(v.x); o.y = f2bf(v.y); o.z = f2bf(v.z); o.w = f2bf(v.w);
    ((ushort4*)out)[i] = o;
  }
}

// mods[row] = te . adaW[row] + adab[row], rows cover NB*6*D
__global__ __launch_bounds__(256) void k_ada(const float* __restrict__ te,
    const float* __restrict__ adaW, const float* __restrict__ adab,
    float* __restrict__ mods){
  int row = blockIdx.x*4 + (threadIdx.x>>6);
  int lane = threadIdx.x & 63;
  const float* wr = adaW + (size_t)row*1024;
  float s = 0.f;
  #pragma unroll
  for (int j=0; j<4; j++){
    int c = lane*4 + j*256;
    float4 a = *(const float4*)(te + c);
    float4 b = *(const float4*)(wr + c);
    s += a.x*b.x + a.y*b.y + a.z*b.z + a.w*b.w;
  }
  #pragma unroll
  for (int off=32; off; off>>=1) s += __shfl_down(s, off);
  if (!lane) mods[row] = s + adab[row];
}

// LayerNorm over D=1024 (one block per row), optional scale/shift modulation, bf16 out
__global__ __launch_bounds__(256) void k_ln_mod(const float* __restrict__ x,
    const float* __restrict__ sh, const float* __restrict__ sc,
    u16* __restrict__ out){
  int row = blockIdx.x, t = threadIdx.x;
  const float* xr = x + (size_t)row*1024;
  float4 v = ((const float4*)xr)[t];
  float s  = v.x+v.y+v.z+v.w;
  float sq = v.x*v.x+v.y*v.y+v.z*v.z+v.w*v.w;
  #pragma unroll
  for (int off=32; off; off>>=1){ s += __shfl_down(s,off); sq += __shfl_down(sq,off); }
  __shared__ float red[8];
  int w = t>>6, lane = t&63;
  if (!lane){ red[w] = s; red[4+w] = sq; }
  __syncthreads();
  s  = red[0]+red[1]+red[2]+red[3];
  sq = red[4]+red[5]+red[6]+red[7];
  float mean = s*(1.f/1024.f);
  float var  = sq*(1.f/1024.f) - mean*mean;
  float rst  = rsqrtf(var + 1e-6f);
  float vv[4] = {v.x, v.y, v.z, v.w};
  ushort4 o;
  u16 ob[4];
  #pragma unroll
  for (int j=0;j<4;j++){
    int col = t*4+j;
    float y = (vv[j]-mean)*rst;
    if (sh) y = y*(1.f + sc[col]) + sh[col];
    ob[j] = f2bf(y);
  }
  o.x=ob[0]; o.y=ob[1]; o.z=ob[2]; o.w=ob[3];
  *(ushort4*)(out + (size_t)row*1024 + t*4) = o;
}

// RoPE in-place on q and k (bf16), rope: [3072][64] fp32 angles
__global__ __launch_bounds__(256) void k_rope(u16* __restrict__ q, u16* __restrict__ k,
    const float* __restrict__ rope){
  int idx = blockIdx.x*256 + threadIdx.x;   // L*H*32 threads
  int d = idx & 31;
  int h = (idx >> 5) & 15;
  int p = idx >> 9;
  const float* rr = rope + (size_t)p*64;
  float a0 = rr[d], a1 = rr[d+32];
  float c0 = cosf(a0), s0 = sinf(a0);
  float c1 = cosf(a1), s1 = sinf(a1);
  size_t o = (size_t)p*1024 + h*64 + d;
  float q0 = bf2f(q[o]), q1 = bf2f(q[o+32]);
  q[o]    = f2bf(q0*c0 - q1*s0);
  q[o+32] = f2bf(q1*c1 + q0*s1);
  float k0 = bf2f(k[o]), k1 = bf2f(k[o+32]);
  k[o]    = f2bf(k0*c0 - k1*s0);
  k[o+32] = f2bf(k1*c1 + k0*s1);
}

// ---------------- GEMM: Y = X(MxK,bf16) . W(NxK,f32->bf16)^T ----------------
// EPI 0: Ybf = X.W^T + b      (bf16 out)
// EPI 1: Ybf = gelu(X.W^T+b)  (bf16 out)
// EPI 2: resout = resin + gate * (X.W^T + b)   (f32 out)
template<int EPI>
__global__ __launch_bounds__(256) void k_gemm_bt(
    const u16* __restrict__ X, const float* __restrict__ W,
    const float* __restrict__ bias,
    u16* __restrict__ Ybf,
    const float* __restrict__ resin, float* __restrict__ resout,
    const float* __restrict__ gate,
    int M, int N, int K)
{
  __shared__ __align__(16) u16 As[128][40];
  __shared__ __align__(16) u16 Bs[128][40];
  int bm = blockIdx.x*128, bn = blockIdx.y*128;
  int t = threadIdx.x;
  int w = t>>6, lane = t&63;
  int wr = (w>>1)*64, wc = (w&1)*64;
  int fr = lane&15, g = lane>>4;
  f32x4 acc[4][4] = {};
  int srow = t>>2;
  int scol = (t&3)*8;
  const u16*  xp = X + (size_t)(bm+srow)*K + scol;
  const float* wp = W + (size_t)(bn+srow)*K + scol;
  for (int k0=0; k0<K; k0+=32){
    #pragma unroll
    for (int it=0; it<2; ++it){
      uint4 av = *(const uint4*)(xp + (size_t)it*64*K + k0);
      *(uint4*)&As[srow+it*64][scol] = av;
      float4 f0 = *(const float4*)(wp + (size_t)it*64*K + k0);
      float4 f1 = *(const float4*)(wp + (size_t)it*64*K + k0 + 4);
      uint4 bw;
      bw.x = (u32)f2bf(f0.x) | ((u32)f2bf(f0.y)<<16);
      bw.y = (u32)f2bf(f0.z) | ((u32)f2bf(f0.w)<<16);
      bw.z = (u32)f2bf(f1.x) | ((u32)f2bf(f1.y)<<16);
      bw.w = (u32)f2bf(f1.z) | ((u32)f2bf(f1.w)<<16);
      *(uint4*)&Bs[srow+it*64][scol] = bw;
    }
    __syncthreads();
    bf16x8 a[4], b[4];
    #pragma unroll
    for (int i=0;i<4;i++) a[i] = *(const bf16x8*)&As[wr+i*16+fr][g*8];
    #pragma unroll
    for (int i=0;i<4;i++) b[i] = *(const bf16x8*)&Bs[wc+i*16+fr][g*8];
    #pragma unroll
    for (int i=0;i<4;i++)
      #pragma unroll
      for (int j=0;j<4;j++)
        acc[i][j] = __builtin_amdgcn_mfma_f32_16x16x32_bf16(a[i], b[j], acc[i][j], 0, 0, 0);
    __syncthreads();
  }
  #pragma unroll
  for (int i=0;i<4;i++){
    #pragma unroll
    for (int j=0;j<4;j++){
      int col = bn + wc + j*16 + fr;
      float bv = bias ? bias[col] : 0.f;
      #pragma unroll
      for (int r=0;r<4;r++){
        int row = bm + wr + i*16 + g*4 + r;
        float y = acc[i][j][r] + bv;
        if (EPI == 0){
          Ybf[(size_t)row*N + col] = f2bf(y);
        } else if (EPI == 1){
          Ybf[(size_t)row*N + col] = f2bf(gelu_exact(y));
        } else {
          float gt = gate ? gate[col] : 1.f;
          resout[(size_t)row*N + col] = resin[(size_t)row*N + col] + gt*y;
        }
      }
    }
  }
}

// ---------------- Flash attention ----------------
// grid (Lq/64, H); 4 waves, each owns 16 q rows. KV tiles of 32.
__global__ __launch_bounds__(256) void k_flash(
    const u16* __restrict__ Q, const u16* __restrict__ Kb, const u16* __restrict__ Vb,
    u16* __restrict__ O, int Lkv)
{
  __shared__ __align__(16) u16 Ks[32][72];
  __shared__ __align__(16) u16 Vt[64][40];
  __shared__ __align__(16) u16 Ps[4][16][40];
  int h = blockIdx.y;
  int q0 = blockIdx.x*64;
  int t = threadIdx.x, w = t>>6, lane = t&63;
  int fr = lane&15, g = lane>>4;
  const u16* qrow = Q + (size_t)(q0 + w*16 + fr)*1024 + h*64;
  bf16x8 aq0 = *(const bf16x8*)(qrow + g*8);
  bf16x8 aq1 = *(const bf16x8*)(qrow + 32 + g*8);
  f32x4 accO[4] = {};
  float m_r[4], l_r[4];
  #pragma unroll
  for (int r=0;r<4;r++){ m_r[r] = -1e30f; l_r[r] = 0.f; }
  int srow = t>>3, scol = (t&7)*8;
  const u16* kp = Kb + (size_t)srow*1024 + h*64 + scol;
  const u16* vp = Vb + (size_t)srow*1024 + h*64 + scol;
  for (int k0=0; k0<Lkv; k0+=32){
    uint4 kv = *(const uint4*)(kp + (size_t)k0*1024);
    *(uint4*)&Ks[srow][scol] = kv;
    uint4 vv = *(const uint4*)(vp + (size_t)k0*1024);
    Vt[scol+0][srow] = (u16)(vv.x);
    Vt[scol+1][srow] = (u16)(vv.x>>16);
    Vt[scol+2][srow] = (u16)(vv.y);
    Vt[scol+3][srow] = (u16)(vv.y>>16);
    Vt[scol+4][srow] = (u16)(vv.z);
    Vt[scol+5][srow] = (u16)(vv.z>>16);
    Vt[scol+6][srow] = (u16)(vv.w);
    Vt[scol+7][srow] = (u16)(vv.w>>16);
    __syncthreads();
    // S = (Q.K^T)*scale : 16 q-rows x 32 kv-cols per wave
    f32x4 s0 = {}, s1 = {};
    {
      bf16x8 b00 = *(const bf16x8*)&Ks[fr][g*8];
      bf16x8 b01 = *(const bf16x8*)&Ks[fr][32+g*8];
      s0 = __builtin_amdgcn_mfma_f32_16x16x32_bf16(aq0, b00, s0, 0,0,0);
      s0 = __builtin_amdgcn_mfma_f32_16x16x32_bf16(aq1, b01, s0, 0,0,0);
      bf16x8 b10 = *(const bf16x8*)&Ks[16+fr][g*8];
      bf16x8 b11 = *(const bf16x8*)&Ks[16+fr][32+g*8];
      s1 = __builtin_amdgcn_mfma_f32_16x16x32_bf16(aq0, b10, s1, 0,0,0);
      s1 = __builtin_amdgcn_mfma_f32_16x16x32_bf16(aq1, b11, s1, 0,0,0);
    }
    #pragma unroll
    for (int r=0;r<4;r++){
      float a0 = s0[r]*0.125f, a1 = s1[r]*0.125f;
      float mt = fmaxf(a0, a1);
      #pragma unroll
      for (int off=1; off<16; off<<=1) mt = fmaxf(mt, __shfl_xor(mt, off));
      float mn = fmaxf(m_r[r], mt);
      float er = __expf(m_r[r] - mn);
      float p0 = __expf(a0 - mn);
      float p1 = __expf(a1 - mn);
      float rs = p0 + p1;
      #pragma unroll
      for (int off=1; off<16; off<<=1) rs += __shfl_xor(rs, off);
      m_r[r] = mn;
      l_r[r] = l_r[r]*er + rs;
      #pragma unroll
      for (int nd=0; nd<4; nd++) accO[nd][r] *= er;
      Ps[w][g*4+r][fr]    = f2bf(p0);
      Ps[w][g*4+r][16+fr] = f2bf(p1);
    }
    bf16x8 ap = *(const bf16x8*)&Ps[w][fr][g*8];
    #pragma unroll
    for (int nd=0; nd<4; nd++){
      bf16x8 bv = *(const bf16x8*)&Vt[nd*16+fr][g*8];
      accO[nd] = __builtin_amdgcn_mfma_f32_16x16x32_bf16(ap, bv, accO[nd], 0,0,0);
    }
    __syncthreads();
  }
  #pragma unroll
  for (int nd=0; nd<4; nd++){
    #pragma unroll
    for (int r=0;r<4;r++){
      int row = q0 + w*16 + g*4 + r;
      O[(size_t)row*1024 + h*64 + nd*16 + fr] = f2bf(accO[nd][r] / l_r[r]);
    }
  }
}

// ---------------- launch ----------------
extern "C" void kernel_launch(void* const* d_in, const int* in_sizes, int n_in,
                              void* d_out, int out_size, void* d_ws, size_t ws_size,
                              hipStream_t stream){
  const float* x_in = (const float*)d_in[0];
  const float* te   = (const float*)d_in[1];
  const float* ctx  = (const float*)d_in[2];
  const float* rope = (const float*)d_in[3];
  const float* adaW = (const float*)d_in[4];
  const float* adab = (const float*)d_in[5];
  const float* sqW  = (const float*)d_in[6];
  const float* skW  = (const float*)d_in[7];
  const float* svW  = (const float*)d_in[8];
  const float* soW  = (const float*)d_in[9];
  const float* sob  = (const float*)d_in[10];
  const float* cqW  = (const float*)d_in[11];
  const float* ckW  = (const float*)d_in[12];
  const float* cvW  = (const float*)d_in[13];
  const float* coW  = (const float*)d_in[14];
  const float* cob  = (const float*)d_in[15];
  const float* f1W  = (const float*)d_in[16];
  const float* f1b  = (const float*)d_in[17];
  const float* f2W  = (const float*)d_in[18];
  const float* f2b  = (const float*)d_in[19];
  float* x = (float*)d_out;

  char* p = (char*)d_ws;
  auto alloc = [&](size_t bytes){ void* r = (void*)p; p += (bytes + 255) & ~(size_t)255; return r; };
  u16* hx   = (u16*)alloc((size_t)3072*1024*2);
  u16* qb   = (u16*)alloc((size_t)3072*1024*2);
  u16* kb   = (u16*)alloc((size_t)3072*1024*2);
  u16* vb   = (u16*)alloc((size_t)3072*1024*2);
  u16* ob   = (u16*)alloc((size_t)3072*1024*2);
  u16* mid  = (u16*)alloc((size_t)3072*4096*2);
  u16* ctxb = (u16*)alloc((size_t)512*1024*2);
  float* mods = (float*)alloc((size_t)2*6144*4);

  k_copy_f32<<<3072, 256, 0, stream>>>(x_in, x, 786432);
  k_cvt_bf16<<<512, 256, 0, stream>>>(ctx, ctxb, 131072);
  k_ada<<<3072, 256, 0, stream>>>(te, adaW, adab, mods);

  for (int i=0; i<2; ++i){
    const float* mi = mods + (size_t)i*6144;
    size_t wo = (size_t)i*1024*1024;
    // --- self attention ---
    k_ln_mod<<<3072,256,0,stream>>>(x, mi+0, mi+1024, hx);
    k_gemm_bt<0><<<dim3(24,8),256,0,stream>>>(hx, sqW+wo, nullptr, qb, nullptr,nullptr,nullptr, 3072,1024,1024);
    k_gemm_bt<0><<<dim3(24,8),256,0,stream>>>(hx, skW+wo, nullptr, kb, nullptr,nullptr,nullptr, 3072,1024,1024);
    k_gemm_bt<0><<<dim3(24,8),256,0,stream>>>(hx, svW+wo, nullptr, vb, nullptr,nullptr,nullptr, 3072,1024,1024);
    k_rope<<<6144,256,0,stream>>>(qb, kb, rope);
    k_flash<<<dim3(48,16),256,0,stream>>>(qb, kb, vb, ob, 3072);
    k_gemm_bt<2><<<dim3(24,8),256,0,stream>>>(ob, soW+wo, sob+(size_t)i*1024, nullptr, x, x, mi+2048, 3072,1024,1024);
    // --- cross attention ---
    k_ln_mod<<<3072,256,0,stream>>>(x, nullptr, nullptr, hx);
    k_gemm_bt<0><<<dim3(24,8),256,0,stream>>>(hx, cqW+wo, nullptr, qb, nullptr,nullptr,nullptr, 3072,1024,1024);
    k_gemm_bt<0><<<dim3(4,8),256,0,stream>>>(ctxb, ckW+wo, nullptr, kb, nullptr,nullptr,nullptr, 512,1024,1024);
    k_gemm_bt<0><<<dim3(4,8),256,0,stream>>>(ctxb, cvW+wo, nullptr, vb, nullptr,nullptr,nullptr, 512,1024,1024);
    k_flash<<<dim3(48,16),256,0,stream>>>(qb, kb, vb, ob, 512);
    k_gemm_bt<2><<<dim3(24,8),256,0,stream>>>(ob, coW+wo, cob+(size_t)i*1024, nullptr, x, x, nullptr, 3072,1024,1024);
    // --- MLP ---
    k_ln_mod<<<3072,256,0,stream>>>(x, mi+3072, mi+4096, hx);
    k_gemm_bt<1><<<dim3(24,32),256,0,stream>>>(hx, f1W+(size_t)i*4096*1024, f1b+(size_t)i*4096, mid, nullptr,nullptr,nullptr, 3072,4096,1024);
    k_gemm_bt<2><<<dim3(24,8),256,0,stream>>>(mid, f2W+(size_t)i*1024*4096, f2b+(size_t)i*1024, nullptr, x, x, mi+5120, 3072,1024,4096);
  }
}

// Round 2
// 1213.491 us; speedup vs baseline: 1.4305x; 1.4305x over previous
//
#include <hip/hip_runtime.h>
#include <math.h>

typedef __attribute__((ext_vector_type(8))) short bf16x8;
typedef __attribute__((ext_vector_type(4))) float f32x4;
typedef unsigned short u16;
typedef unsigned int u32;

#define DEV static __device__ __forceinline__

typedef __attribute__((address_space(3))) u32 lds_u32;
typedef const __attribute__((address_space(1))) u32 glb_u32;

DEV void gload16(const void* g, void* l){
  __builtin_amdgcn_global_load_lds((glb_u32*)g, (lds_u32*)l, 16, 0, 0);
}

DEV u16 f2bf(float f){
  u32 u = __builtin_bit_cast(u32, f);
  u32 r = (u + 0x7fffu + ((u >> 16) & 1u)) >> 16;
  return (u16)r;
}
DEV float bf2f(u16 h){
  u32 u = ((u32)h) << 16;
  return __builtin_bit_cast(float, u);
}
DEV float gelu_exact(float x){ return 0.5f*x*(1.f+erff(x*0.70710678118654752f)); }

// ---------------- elementwise ----------------
__global__ __launch_bounds__(256) void k_copy_f32(const float* __restrict__ in, float* __restrict__ out, int n4){
  int i = blockIdx.x*256 + threadIdx.x;
  if (i < n4) ((float4*)out)[i] = ((const float4*)in)[i];
}

__global__ __launch_bounds__(256) void k_cvt_bf16(const float* __restrict__ in, u16* __restrict__ out, int n4){
  int i = blockIdx.x*256 + threadIdx.x;
  if (i < n4){
    float4 v = ((const float4*)in)[i];
    ushort4 o;
    o.x = f2bf(v.x); o.y = f2bf(v.y); o.z = f2bf(v.z); o.w = f2bf(v.w);
    ((ushort4*)out)[i] = o;
  }
}

// mods[row] = te . adaW[row] + adab[row]
__global__ __launch_bounds__(256) void k_ada(const float* __restrict__ te,
    const float* __restrict__ adaW, const float* __restrict__ adab,
    float* __restrict__ mods){
  int row = blockIdx.x*4 + (threadIdx.x>>6);
  int lane = threadIdx.x & 63;
  const float* wr = adaW + (size_t)row*1024;
  float s = 0.f;
  #pragma unroll
  for (int j=0; j<4; j++){
    int c = lane*4 + j*256;
    float4 a = *(const float4*)(te + c);
    float4 b = *(const float4*)(wr + c);
    s += a.x*b.x + a.y*b.y + a.z*b.z + a.w*b.w;
  }
  #pragma unroll
  for (int off=32; off; off>>=1) s += __shfl_down(s, off);
  if (!lane) mods[row] = s + adab[row];
}

// LayerNorm over D=1024, optional modulation, bf16 out
__global__ __launch_bounds__(256) void k_ln_mod(const float* __restrict__ x,
    const float* __restrict__ sh, const float* __restrict__ sc,
    u16* __restrict__ out){
  int row = blockIdx.x, t = threadIdx.x;
  const float* xr = x + (size_t)row*1024;
  float4 v = ((const float4*)xr)[t];
  float s  = v.x+v.y+v.z+v.w;
  float sq = v.x*v.x+v.y*v.y+v.z*v.z+v.w*v.w;
  #pragma unroll
  for (int off=32; off; off>>=1){ s += __shfl_down(s,off); sq += __shfl_down(sq,off); }
  __shared__ float red[8];
  int w = t>>6, lane = t&63;
  if (!lane){ red[w] = s; red[4+w] = sq; }
  __syncthreads();
  s  = red[0]+red[1]+red[2]+red[3];
  sq = red[4]+red[5]+red[6]+red[7];
  float mean = s*(1.f/1024.f);
  float var  = sq*(1.f/1024.f) - mean*mean;
  float rst  = rsqrtf(var + 1e-6f);
  float vv[4] = {v.x, v.y, v.z, v.w};
  ushort4 o;
  u16 ob[4];
  #pragma unroll
  for (int j=0;j<4;j++){
    int col = t*4+j;
    float y = (vv[j]-mean)*rst;
    if (sh) y = y*(1.f + sc[col]) + sh[col];
    ob[j] = f2bf(y);
  }
  o.x=ob[0]; o.y=ob[1]; o.z=ob[2]; o.w=ob[3];
  *(ushort4*)(out + (size_t)row*1024 + t*4) = o;
}

// RoPE in-place on q and k (bf16)
__global__ __launch_bounds__(256) void k_rope(u16* __restrict__ q, u16* __restrict__ k,
    const float* __restrict__ rope){
  int idx = blockIdx.x*256 + threadIdx.x;
  int d = idx & 31;
  int h = (idx >> 5) & 15;
  int p = idx >> 9;
  const float* rr = rope + (size_t)p*64;
  float a0 = rr[d], a1 = rr[d+32];
  float c0 = cosf(a0), s0 = sinf(a0);
  float c1 = cosf(a1), s1 = sinf(a1);
  size_t o = (size_t)p*1024 + h*64 + d;
  float q0 = bf2f(q[o]), q1 = bf2f(q[o+32]);
  q[o]    = f2bf(q0*c0 - q1*s0);
  q[o+32] = f2bf(q1*c1 + q0*s1);
  float k0 = bf2f(k[o]), k1 = bf2f(k[o+32]);
  k[o]    = f2bf(k0*c0 - k1*s0);
  k[o+32] = f2bf(k1*c1 + k0*s1);
}

// ---------------- GEMM: Y = X(MxK,bf16) . W(NxK)^T ----------------
// WSRC 0: W is bf16, both operands via global_load_lds (m97 structure)
// WSRC 1: W is f32, converted in-flight (fallback if ws too small)
// EPI 0: bf16 out   EPI 1: gelu bf16 out
// EPI 2: resout = resin + gate*(y)   f32
// EPI 3: transpose store bf16: Yout[col*M + row]
template<int EPI, int WSRC>
__global__ __launch_bounds__(256) void k_gemm(
    const u16* __restrict__ X, const void* __restrict__ Wv,
    const float* __restrict__ bias,
    u16* __restrict__ Yout,
    const float* __restrict__ resin, float* __restrict__ resout,
    const float* __restrict__ gate,
    int M, int N, int K)
{
  constexpr int BPAD = (WSRC==0) ? 32 : 40;
  __shared__ __align__(16) u16 As[128][32];
  __shared__ __align__(16) u16 Bs[128][BPAD];
  int bm = blockIdx.x*128, bn = blockIdx.y*128;
  int t = threadIdx.x;
  int w = t>>6, lane = t&63;
  int wr = (w>>1)*64, wc = (w&1)*64;
  int fr = lane&15, g = lane>>4;
  f32x4 acc[4][4] = {};
  int arow = lane>>2;           // 0..15 row within 16-row chunk
  int acol = (lane&3)*8;        // element col within 32
  const float* Wf = (const float*)Wv;
  const u16*   Wb = (const u16*)Wv;
  int srow = t>>2, scol = (t&3)*8;   // WSRC1 staging
  for (int k0=0; k0<K; k0+=32){
    #pragma unroll
    for (int inst=0; inst<2; ++inst){
      int r = w*32 + inst*16 + arow;
      gload16(X + (size_t)(bm+r)*K + k0 + acol, &As[w*32+inst*16][0]);
      if (WSRC==0)
        gload16(Wb + (size_t)(bn+r)*K + k0 + acol, &Bs[w*32+inst*16][0]);
    }
    if (WSRC==1){
      #pragma unroll
      for (int it=0; it<2; ++it){
        const float* wp = Wf + (size_t)(bn+srow+it*64)*K + k0 + scol;
        float4 f0 = *(const float4*)(wp);
        float4 f1 = *(const float4*)(wp+4);
        uint4 bw;
        bw.x = (u32)f2bf(f0.x) | ((u32)f2bf(f0.y)<<16);
        bw.y = (u32)f2bf(f0.z) | ((u32)f2bf(f0.w)<<16);
        bw.z = (u32)f2bf(f1.x) | ((u32)f2bf(f1.y)<<16);
        bw.w = (u32)f2bf(f1.z) | ((u32)f2bf(f1.w)<<16);
        *(uint4*)&Bs[srow+it*64][scol] = bw;
      }
    }
    __syncthreads();
    bf16x8 a[4], b[4];
    #pragma unroll
    for (int i=0;i<4;i++) a[i] = *(const bf16x8*)&As[wr+i*16+fr][g*8];
    #pragma unroll
    for (int i=0;i<4;i++) b[i] = *(const bf16x8*)&Bs[wc+i*16+fr][g*8];
    #pragma unroll
    for (int i=0;i<4;i++)
      #pragma unroll
      for (int j=0;j<4;j++)
        acc[i][j] = __builtin_amdgcn_mfma_f32_16x16x32_bf16(a[i], b[j], acc[i][j], 0, 0, 0);
    __syncthreads();
  }
  #pragma unroll
  for (int i=0;i<4;i++){
    #pragma unroll
    for (int j=0;j<4;j++){
      int col = bn + wc + j*16 + fr;
      float bv = bias ? bias[col] : 0.f;
      #pragma unroll
      for (int r=0;r<4;r++){
        int row = bm + wr + i*16 + g*4 + r;
        float y = acc[i][j][r] + bv;
        if (EPI == 0){
          Yout[(size_t)row*N + col] = f2bf(y);
        } else if (EPI == 1){
          Yout[(size_t)row*N + col] = f2bf(gelu_exact(y));
        } else if (EPI == 2){
          float gt = gate ? gate[col] : 1.f;
          resout[(size_t)row*N + col] = resin[(size_t)row*N + col] + gt*y;
        } else {
          Yout[(size_t)col*M + row] = f2bf(y);   // transpose (VT)
        }
      }
    }
  }
}

// ---------------- Flash attention ----------------
// grid (Lq/64, H); 4 waves x 16 q-rows; KV tiles of 64.
// K: [L][1024] bf16 (rope'd); VT: [1024][Lkv] bf16 (pre-transposed).
__global__ __launch_bounds__(256) void k_flash(
    const u16* __restrict__ Q, const u16* __restrict__ Kb, const u16* __restrict__ VT,
    u16* __restrict__ O, int Lkv)
{
  __shared__ __align__(16) u16 Ks[64][64];
  __shared__ __align__(16) u16 Vs[64][64];
  __shared__ __align__(16) u16 Ps[4][16][72];
  int h = blockIdx.y;
  int q0 = blockIdx.x*64;
  int t = threadIdx.x, w = t>>6, lane = t&63;
  int fr = lane&15, g = lane>>4;
  const u16* qrow = Q + (size_t)(q0 + w*16 + fr)*1024 + h*64;
  bf16x8 aq0 = *(const bf16x8*)(qrow + g*8);
  bf16x8 aq1 = *(const bf16x8*)(qrow + 32 + g*8);
  f32x4 accO[4] = {};
  float m_r[4], l_r[4];
  #pragma unroll
  for (int r=0;r<4;r++){ m_r[r] = -1e30f; l_r[r] = 0.f; }
  int slot = lane & 7, rop = lane >> 3;
  for (int k0=0; k0<Lkv; k0+=64){
    #pragma unroll
    for (int inst=0; inst<2; ++inst){
      int row = w*16 + inst*8 + rop;
      int ss = slot ^ (row & 7);   // inverse-swizzled source chunk
      gload16(Kb + (size_t)(k0+row)*1024 + h*64 + ss*8, &Ks[w*16+inst*8][0]);
      gload16(VT + (size_t)(h*64+row)*Lkv + k0 + ss*8, &Vs[w*16+inst*8][0]);
    }
    __syncthreads();
    // S = Q.K^T
    f32x4 sc4[4] = {};
    #pragma unroll
    for (int kb=0;kb<4;kb++){
      int rowK = kb*16 + fr;
      bf16x8 b0 = *(const bf16x8*)&Ks[rowK][((g  ) ^ (rowK&7))*8];
      bf16x8 b1 = *(const bf16x8*)&Ks[rowK][((4+g) ^ (rowK&7))*8];
      sc4[kb] = __builtin_amdgcn_mfma_f32_16x16x32_bf16(aq0, b0, sc4[kb], 0,0,0);
      sc4[kb] = __builtin_amdgcn_mfma_f32_16x16x32_bf16(aq1, b1, sc4[kb], 0,0,0);
    }
    #pragma unroll
    for (int r=0;r<4;r++){
      float a0 = sc4[0][r]*0.125f, a1 = sc4[1][r]*0.125f;
      float a2 = sc4[2][r]*0.125f, a3 = sc4[3][r]*0.125f;
      float mt = fmaxf(fmaxf(a0,a1), fmaxf(a2,a3));
      #pragma unroll
      for (int off=1; off<16; off<<=1) mt = fmaxf(mt, __shfl_xor(mt, off));
      float mn = fmaxf(m_r[r], mt);
      float er = __expf(m_r[r] - mn);
      float p0 = __expf(a0 - mn), p1 = __expf(a1 - mn);
      float p2 = __expf(a2 - mn), p3 = __expf(a3 - mn);
      float rs = p0 + p1 + p2 + p3;
      #pragma unroll
      for (int off=1; off<16; off<<=1) rs += __shfl_xor(rs, off);
      m_r[r] = mn;
      l_r[r] = l_r[r]*er + rs;
      #pragma unroll
      for (int nd=0; nd<4; nd++) accO[nd][r] *= er;
      int q = g*4 + r;
      Ps[w][q][fr]    = f2bf(p0);
      Ps[w][q][16+fr] = f2bf(p1);
      Ps[w][q][32+fr] = f2bf(p2);
      Ps[w][q][48+fr] = f2bf(p3);
    }
    bf16x8 ap0 = *(const bf16x8*)&Ps[w][fr][g*8];
    bf16x8 ap1 = *(const bf16x8*)&Ps[w][fr][32+g*8];
    #pragma unroll
    for (int nd=0; nd<4; nd++){
      int rowV = nd*16 + fr;
      bf16x8 b0 = *(const bf16x8*)&Vs[rowV][((g  ) ^ (rowV&7))*8];
      bf16x8 b1 = *(const bf16x8*)&Vs[rowV][((4+g) ^ (rowV&7))*8];
      accO[nd] = __builtin_amdgcn_mfma_f32_16x16x32_bf16(ap0, b0, accO[nd], 0,0,0);
      accO[nd] = __builtin_amdgcn_mfma_f32_16x16x32_bf16(ap1, b1, accO[nd], 0,0,0);
    }
    __syncthreads();
  }
  #pragma unroll
  for (int nd=0; nd<4; nd++){
    #pragma unroll
    for (int r=0;r<4;r++){
      int row = q0 + w*16 + g*4 + r;
      O[(size_t)row*1024 + h*64 + nd*16 + fr] = f2bf(accO[nd][r] / l_r[r]);
    }
  }
}

// ---------------- launch ----------------
extern "C" void kernel_launch(void* const* d_in, const int* in_sizes, int n_in,
                              void* d_out, int out_size, void* d_ws, size_t ws_size,
                              hipStream_t stream){
  const float* x_in = (const float*)d_in[0];
  const float* te   = (const float*)d_in[1];
  const float* ctx  = (const float*)d_in[2];
  const float* rope = (const float*)d_in[3];
  const float* adaW = (const float*)d_in[4];
  const float* adab = (const float*)d_in[5];
  const float* sqW  = (const float*)d_in[6];
  const float* skW  = (const float*)d_in[7];
  const float* svW  = (const float*)d_in[8];
  const float* soW  = (const float*)d_in[9];
  const float* sob  = (const float*)d_in[10];
  const float* cqW  = (const float*)d_in[11];
  const float* ckW  = (const float*)d_in[12];
  const float* cvW  = (const float*)d_in[13];
  const float* coW  = (const float*)d_in[14];
  const float* cob  = (const float*)d_in[15];
  const float* f1W  = (const float*)d_in[16];
  const float* f1b  = (const float*)d_in[17];
  const float* f2W  = (const float*)d_in[18];
  const float* f2b  = (const float*)d_in[19];
  float* x = (float*)d_out;

  char* p = (char*)d_ws;
  size_t used = 0;
  auto alloc = [&](size_t bytes){
    void* r = (void*)(p + used);
    used += (bytes + 255) & ~(size_t)255;
    return r;
  };
  u16* hx   = (u16*)alloc((size_t)3072*1024*2);
  u16* qb   = (u16*)alloc((size_t)3072*1024*2);
  u16* kb   = (u16*)alloc((size_t)3072*1024*2);
  u16* vt   = (u16*)alloc((size_t)1024*3072*2);
  u16* ob   = (u16*)alloc((size_t)3072*1024*2);
  u16* mid  = (u16*)alloc((size_t)3072*4096*2);
  u16* ctxb = (u16*)alloc((size_t)512*1024*2);
  float* mods = (float*)alloc((size_t)2*6144*4);
  size_t base_used = used;
  const size_t NW_SMALL = (size_t)2*1024*1024;   // elems per [NB,D,D] array
  const size_t NW_BIG   = (size_t)2*4096*1024;   // elems per [NB,DFF,D] array
  size_t wbytes = (8*NW_SMALL + 2*NW_BIG)*2;
  bool pre = (base_used + wbytes + 4096) <= ws_size;

  u16 *sqWb=nullptr,*skWb=nullptr,*svWb=nullptr,*soWb=nullptr,
      *cqWb=nullptr,*ckWb=nullptr,*cvWb=nullptr,*coWb=nullptr,
      *f1Wb=nullptr,*f2Wb=nullptr;
  if (pre){
    sqWb=(u16*)alloc(NW_SMALL*2); skWb=(u16*)alloc(NW_SMALL*2);
    svWb=(u16*)alloc(NW_SMALL*2); soWb=(u16*)alloc(NW_SMALL*2);
    cqWb=(u16*)alloc(NW_SMALL*2); ckWb=(u16*)alloc(NW_SMALL*2);
    cvWb=(u16*)alloc(NW_SMALL*2); coWb=(u16*)alloc(NW_SMALL*2);
    f1Wb=(u16*)alloc(NW_BIG*2);   f2Wb=(u16*)alloc(NW_BIG*2);
    auto CVT = [&](const float* s, u16* d, size_t n){
      k_cvt_bf16<<<(int)(n/1024), 256, 0, stream>>>(s, d, (int)(n/4));
    };
    CVT(sqW,sqWb,NW_SMALL); CVT(skW,skWb,NW_SMALL);
    CVT(svW,svWb,NW_SMALL); CVT(soW,soWb,NW_SMALL);
    CVT(cqW,cqWb,NW_SMALL); CVT(ckW,ckWb,NW_SMALL);
    CVT(cvW,cvWb,NW_SMALL); CVT(coW,coWb,NW_SMALL);
    CVT(f1W,f1Wb,NW_BIG);   CVT(f2W,f2Wb,NW_BIG);
  }

  auto GEMM = [&](int epi, const u16* Xp, const void* Wb_, const void* Wf_,
                  const float* bi, u16* Yp, const float* ri, float* ro,
                  const float* gt, int M, int N, int K){
    dim3 gr(M/128, N/128);
    const void* Wp = pre ? Wb_ : Wf_;
    if (pre){
      switch(epi){
        case 0: k_gemm<0,0><<<gr,256,0,stream>>>(Xp,Wp,bi,Yp,ri,ro,gt,M,N,K); break;
        case 1: k_gemm<1,0><<<gr,256,0,stream>>>(Xp,Wp,bi,Yp,ri,ro,gt,M,N,K); break;
        case 2: k_gemm<2,0><<<gr,256,0,stream>>>(Xp,Wp,bi,Yp,ri,ro,gt,M,N,K); break;
        default:k_gemm<3,0><<<gr,256,0,stream>>>(Xp,Wp,bi,Yp,ri,ro,gt,M,N,K); break;
      }
    } else {
      switch(epi){
        case 0: k_gemm<0,1><<<gr,256,0,stream>>>(Xp,Wp,bi,Yp,ri,ro,gt,M,N,K); break;
        case 1: k_gemm<1,1><<<gr,256,0,stream>>>(Xp,Wp,bi,Yp,ri,ro,gt,M,N,K); break;
        case 2: k_gemm<2,1><<<gr,256,0,stream>>>(Xp,Wp,bi,Yp,ri,ro,gt,M,N,K); break;
        default:k_gemm<3,1><<<gr,256,0,stream>>>(Xp,Wp,bi,Yp,ri,ro,gt,M,N,K); break;
      }
    }
  };

  k_copy_f32<<<3072, 256, 0, stream>>>(x_in, x, 786432);
  k_cvt_bf16<<<512, 256, 0, stream>>>(ctx, ctxb, 131072);
  k_ada<<<3072, 256, 0, stream>>>(te, adaW, adab, mods);

  for (int i=0; i<2; ++i){
    const float* mi = mods + (size_t)i*6144;
    size_t wo = (size_t)i*1024*1024;
    size_t wof = (size_t)i*4096*1024;
    // --- self attention ---
    k_ln_mod<<<3072,256,0,stream>>>(x, mi+0, mi+1024, hx);
    GEMM(0, hx, sqWb?sqWb+wo:nullptr, sqW+wo, nullptr, qb, nullptr,nullptr,nullptr, 3072,1024,1024);
    GEMM(0, hx, skWb?skWb+wo:nullptr, skW+wo, nullptr, kb, nullptr,nullptr,nullptr, 3072,1024,1024);
    GEMM(3, hx, svWb?svWb+wo:nullptr, svW+wo, nullptr, vt, nullptr,nullptr,nullptr, 3072,1024,1024);
    k_rope<<<6144,256,0,stream>>>(qb, kb, rope);
    k_flash<<<dim3(48,16),256,0,stream>>>(qb, kb, vt, ob, 3072);
    GEMM(2, ob, soWb?soWb+wo:nullptr, soW+wo, sob+(size_t)i*1024, nullptr, x, x, mi+2048, 3072,1024,1024);
    // --- cross attention ---
    k_ln_mod<<<3072,256,0,stream>>>(x, nullptr, nullptr, hx);
    GEMM(0, hx,   cqWb?cqWb+wo:nullptr, cqW+wo, nullptr, qb, nullptr,nullptr,nullptr, 3072,1024,1024);
    GEMM(0, ctxb, ckWb?ckWb+wo:nullptr, ckW+wo, nullptr, kb, nullptr,nullptr,nullptr,  512,1024,1024);
    GEMM(3, ctxb, cvWb?cvWb+wo:nullptr, cvW+wo, nullptr, vt, nullptr,nullptr,nullptr,  512,1024,1024);
    k_flash<<<dim3(48,16),256,0,stream>>>(qb, kb, vt, ob, 512);
    GEMM(2, ob, coWb?coWb+wo:nullptr, coW+wo, cob+(size_t)i*1024, nullptr, x, x, nullptr, 3072,1024,1024);
    // --- MLP ---
    k_ln_mod<<<3072,256,0,stream>>>(x, mi+3072, mi+4096, hx);
    GEMM(1, hx, f1Wb?f1Wb+wof:nullptr, f1W+wof, f1b+(size_t)i*4096, mid, nullptr,nullptr,nullptr, 3072,4096,1024);
    GEMM(2, mid, f2Wb?f2Wb+wof:nullptr, f2W+wof, f2b+(size_t)i*1024, nullptr, x, x, mi+5120, 3072,1024,4096);
  }
}

// Round 3
// 948.116 us; speedup vs baseline: 1.8309x; 1.2799x over previous
//
#include <hip/hip_runtime.h>
#include <math.h>

typedef __attribute__((ext_vector_type(8))) short bf16x8;
typedef __attribute__((ext_vector_type(4))) float f32x4;
typedef unsigned short u16;
typedef unsigned int u32;

#define DEV static __device__ __forceinline__

typedef __attribute__((address_space(3))) u32 lds_u32;
typedef const __attribute__((address_space(1))) u32 glb_u32;

DEV void gload16(const void* g, void* l){
  __builtin_amdgcn_global_load_lds((glb_u32*)g, (lds_u32*)l, 16, 0, 0);
}

DEV u16 f2bf(float f){
  u32 u = __builtin_bit_cast(u32, f);
  u32 r = (u + 0x7fffu + ((u >> 16) & 1u)) >> 16;
  return (u16)r;
}
DEV float bf2f(u16 h){
  u32 u = ((u32)h) << 16;
  return __builtin_bit_cast(float, u);
}
// cheap pack of two f32 -> two bf16 in one u32 (round-nearest, ties up)
DEV u32 pack2(float a, float b){
  u32 ua = (__builtin_bit_cast(u32, a) + 0x8000u) >> 16;
  u32 ub = (__builtin_bit_cast(u32, b) + 0x8000u) & 0xffff0000u;
  return ua | ub;
}
DEV float gelu_exact(float x){ return 0.5f*x*(1.f+erff(x*0.70710678118654752f)); }

// bijective XCD-aware block remap (requires gx*gy % 8 == 0, else identity)
DEV void xcd_remap(int &bx, int &by){
  int gx = gridDim.x, gy = gridDim.y;
  int n = gx*gy;
  if ((n & 7) == 0){
    int id = by*gx + bx;
    int q = n >> 3;
    int sid = (id & 7)*q + (id >> 3);
    bx = sid % gx;
    by = sid / gx;
  }
}

// ---------------- elementwise ----------------
__global__ __launch_bounds__(256) void k_copy_f32(const float* __restrict__ in, float* __restrict__ out, int n4){
  int i = blockIdx.x*256 + threadIdx.x;
  if (i < n4) ((float4*)out)[i] = ((const float4*)in)[i];
}

__global__ __launch_bounds__(256) void k_cvt_bf16(const float* __restrict__ in, u16* __restrict__ out, int n4){
  int i = blockIdx.x*256 + threadIdx.x;
  if (i < n4){
    float4 v = ((const float4*)in)[i];
    ushort4 o;
    o.x = f2bf(v.x); o.y = f2bf(v.y); o.z = f2bf(v.z); o.w = f2bf(v.w);
    ((ushort4*)out)[i] = o;
  }
}

__global__ __launch_bounds__(256) void k_ada(const float* __restrict__ te,
    const float* __restrict__ adaW, const float* __restrict__ adab,
    float* __restrict__ mods){
  int row = blockIdx.x*4 + (threadIdx.x>>6);
  int lane = threadIdx.x & 63;
  const float* wr = adaW + (size_t)row*1024;
  float s = 0.f;
  #pragma unroll
  for (int j=0; j<4; j++){
    int c = lane*4 + j*256;
    float4 a = *(const float4*)(te + c);
    float4 b = *(const float4*)(wr + c);
    s += a.x*b.x + a.y*b.y + a.z*b.z + a.w*b.w;
  }
  #pragma unroll
  for (int off=32; off; off>>=1) s += __shfl_down(s, off);
  if (!lane) mods[row] = s + adab[row];
}

__global__ __launch_bounds__(256) void k_ln_mod(const float* __restrict__ x,
    const float* __restrict__ sh, const float* __restrict__ sc,
    u16* __restrict__ out){
  int row = blockIdx.x, t = threadIdx.x;
  const float* xr = x + (size_t)row*1024;
  float4 v = ((const float4*)xr)[t];
  float s  = v.x+v.y+v.z+v.w;
  float sq = v.x*v.x+v.y*v.y+v.z*v.z+v.w*v.w;
  #pragma unroll
  for (int off=32; off; off>>=1){ s += __shfl_down(s,off); sq += __shfl_down(sq,off); }
  __shared__ float red[8];
  int w = t>>6, lane = t&63;
  if (!lane){ red[w] = s; red[4+w] = sq; }
  __syncthreads();
  s  = red[0]+red[1]+red[2]+red[3];
  sq = red[4]+red[5]+red[6]+red[7];
  float mean = s*(1.f/1024.f);
  float var  = sq*(1.f/1024.f) - mean*mean;
  float rst  = rsqrtf(var + 1e-6f);
  float vv[4] = {v.x, v.y, v.z, v.w};
  ushort4 o;
  u16 ob[4];
  #pragma unroll
  for (int j=0;j<4;j++){
    int col = t*4+j;
    float y = (vv[j]-mean)*rst;
    if (sh) y = y*(1.f + sc[col]) + sh[col];
    ob[j] = f2bf(y);
  }
  o.x=ob[0]; o.y=ob[1]; o.z=ob[2]; o.w=ob[3];
  *(ushort4*)(out + (size_t)row*1024 + t*4) = o;
}

// RoPE; q additionally scaled by 1/sqrt(64) (folded attention scale)
__global__ __launch_bounds__(256) void k_rope(u16* __restrict__ q, u16* __restrict__ k,
    const float* __restrict__ rope){
  int idx = blockIdx.x*256 + threadIdx.x;
  int d = idx & 31;
  int h = (idx >> 5) & 15;
  int p = idx >> 9;
  const float* rr = rope + (size_t)p*64;
  float a0 = rr[d], a1 = rr[d+32];
  float c0 = cosf(a0), s0 = sinf(a0);
  float c1 = cosf(a1), s1 = sinf(a1);
  size_t o = (size_t)p*1024 + h*64 + d;
  float q0 = bf2f(q[o]), q1 = bf2f(q[o+32]);
  q[o]    = f2bf((q0*c0 - q1*s0)*0.125f);
  q[o+32] = f2bf((q1*c1 + q0*s1)*0.125f);
  float k0 = bf2f(k[o]), k1 = bf2f(k[o+32]);
  k[o]    = f2bf(k0*c0 - k1*s0);
  k[o+32] = f2bf(k1*c1 + k0*s1);
}

// ---------------- shared GEMM mainloop (bf16 W, dbuf + prefetch) ----------------
// As/Bs: u16[2*128*32]. Computes acc(4x4 frags) for this thread's wave tile.
DEV void gemm_loop(const u16* __restrict__ X, const u16* __restrict__ W,
                   int bm, int bn, int K, u16* As, u16* Bs, f32x4 acc[4][4])
{
  int t = threadIdx.x;
  int w = t>>6, lane = t&63;
  int wr = (w>>1)*64, wc = (w&1)*64;
  int fr = lane&15, g = lane>>4;
  int arow = lane>>2, acol = (lane&3)*8;
  const u16* xp = X + (size_t)(bm + w*32 + arow)*K + acol;
  const u16* wp = W + (size_t)(bn + w*32 + arow)*K + acol;
  int nk = K >> 5;
  // prologue stage
  {
    u16* a = As + w*1024; u16* b = Bs + w*1024;
    gload16(xp, a);             gload16(xp + (size_t)16*K, a + 512);
    gload16(wp, b);             gload16(wp + (size_t)16*K, b + 512);
  }
  for (int kt = 0; kt < nk; ++kt){
    __syncthreads();
    int cur = kt & 1;
    if (kt + 1 < nk){
      int nb = cur ^ 1;
      int k0 = (kt+1) << 5;
      u16* a = As + nb*4096 + w*1024; u16* b = Bs + nb*4096 + w*1024;
      gload16(xp + k0, a);        gload16(xp + k0 + (size_t)16*K, a + 512);
      gload16(wp + k0, b);        gload16(wp + k0 + (size_t)16*K, b + 512);
    }
    const u16* ab = As + cur*4096;
    const u16* bb = Bs + cur*4096;
    bf16x8 a[4], b[4];
    #pragma unroll
    for (int i=0;i<4;i++) a[i] = *(const bf16x8*)(ab + (wr+i*16+fr)*32 + g*8);
    #pragma unroll
    for (int i=0;i<4;i++) b[i] = *(const bf16x8*)(bb + (wc+i*16+fr)*32 + g*8);
    #pragma unroll
    for (int i=0;i<4;i++)
      #pragma unroll
      for (int j=0;j<4;j++)
        acc[i][j] = __builtin_amdgcn_mfma_f32_16x16x32_bf16(a[i], b[j], acc[i][j], 0, 0, 0);
  }
}

// ---------------- standalone GEMM (bf16 W): EPI 1 gelu, 2 gated-residual, 4 scaled ----------------
template<int EPI>
__global__ __launch_bounds__(256) void k_gemm_bf16(
    const u16* __restrict__ X, const u16* __restrict__ W,
    const float* __restrict__ bias,
    u16* __restrict__ Yout,
    const float* __restrict__ resin, float* __restrict__ resout,
    const float* __restrict__ gate,
    int M, int N, int K)
{
  __shared__ __align__(16) u16 As[2*128*32];
  __shared__ __align__(16) u16 Bs[2*128*32];
  int bx = blockIdx.x, by = blockIdx.y;
  xcd_remap(bx, by);
  int bm = bx*128, bn = by*128;
  f32x4 acc[4][4] = {};
  gemm_loop(X, W, bm, bn, K, As, Bs, acc);
  int lane = threadIdx.x & 63, w = threadIdx.x>>6;
  int wr = (w>>1)*64, wc = (w&1)*64;
  int fr = lane&15, g = lane>>4;
  #pragma unroll
  for (int i=0;i<4;i++){
    #pragma unroll
    for (int j=0;j<4;j++){
      int col = bn + wc + j*16 + fr;
      float bv = bias ? bias[col] : 0.f;
      #pragma unroll
      for (int r=0;r<4;r++){
        int row = bm + wr + i*16 + g*4 + r;
        float y = acc[i][j][r] + bv;
        if (EPI == 1){
          Yout[(size_t)row*N + col] = f2bf(gelu_exact(y));
        } else if (EPI == 2){
          float gt = gate ? gate[col] : 1.f;
          resout[(size_t)row*N + col] = resin[(size_t)row*N + col] + gt*y;
        } else {
          Yout[(size_t)row*N + col] = f2bf(y*0.125f);
        }
      }
    }
  }
}

// ---------------- fused multi-output GEMM ----------------
// MODE 0: QKV  (W0,W1,W2; q->Y0, k->Y1, v->VT transposed)  grid (M/128, 24)
// MODE 1: KV   (W0,W1;    k->Y0, v->VT transposed)         grid (M/128, 16)
template<int MODE>
__global__ __launch_bounds__(256) void k_qkv(
    const u16* __restrict__ X,
    const u16* __restrict__ W0, const u16* __restrict__ W1, const u16* __restrict__ W2,
    u16* __restrict__ Y0, u16* __restrict__ Y1, u16* __restrict__ VT,
    int M, int ldvt)
{
  __shared__ __align__(16) u16 As[2*128*32];
  __shared__ __align__(16) u16 Bs[2*128*32];
  int bx = blockIdx.x, by = blockIdx.y;
  xcd_remap(bx, by);
  int bm = bx*128, bn = by*128;
  int sel = bn >> 10;
  int bnl = bn & 1023;
  const u16* W = (MODE==0) ? (sel==0 ? W0 : (sel==1 ? W1 : W2))
                           : (sel==0 ? W0 : W1);
  f32x4 acc[4][4] = {};
  {
    // same loop, W row index local to segment
    gemm_loop(X, W, bm, bnl, 1024, As, Bs, acc);
  }
  int lane = threadIdx.x & 63, w = threadIdx.x>>6;
  int wr = (w>>1)*64, wc = (w&1)*64;
  int fr = lane&15, g = lane>>4;
  const int lastSel = (MODE==0) ? 2 : 1;
  if (sel < lastSel){
    u16* Y = (sel==0) ? Y0 : Y1;
    #pragma unroll
    for (int i=0;i<4;i++)
      #pragma unroll
      for (int j=0;j<4;j++){
        int col = bnl + wc + j*16 + fr;
        #pragma unroll
        for (int r=0;r<4;r++){
          int row = bm + wr + i*16 + g*4 + r;
          Y[(size_t)row*1024 + col] = f2bf(acc[i][j][r]);
        }
      }
  } else {
    // transpose store: VT[col][row], 4 consecutive rows per lane -> 8B store
    #pragma unroll
    for (int i=0;i<4;i++)
      #pragma unroll
      for (int j=0;j<4;j++){
        int col = bnl + wc + j*16 + fr;
        int row0 = bm + wr + i*16 + g*4;
        uint2 pk;
        pk.x = pack2(acc[i][j][0], acc[i][j][1]);
        pk.y = pack2(acc[i][j][2], acc[i][j][3]);
        *(uint2*)(VT + (size_t)col*ldvt + row0) = pk;
      }
  }
}

// ---------------- fallback GEMM (f32 weights in-flight) ----------------
template<int EPI>
__global__ __launch_bounds__(256) void k_gemm_f32(
    const u16* __restrict__ X, const float* __restrict__ W,
    const float* __restrict__ bias,
    u16* __restrict__ Yout,
    const float* __restrict__ resin, float* __restrict__ resout,
    const float* __restrict__ gate,
    int M, int N, int K)
{
  __shared__ __align__(16) u16 As[128][32];
  __shared__ __align__(16) u16 Bs[128][40];
  int bx = blockIdx.x, by = blockIdx.y;
  xcd_remap(bx, by);
  int bm = bx*128, bn = by*128;
  int t = threadIdx.x;
  int w = t>>6, lane = t&63;
  int wr = (w>>1)*64, wc = (w&1)*64;
  int fr = lane&15, g = lane>>4;
  f32x4 acc[4][4] = {};
  int arow = lane>>2, acol = (lane&3)*8;
  int srow = t>>2, scol = (t&3)*8;
  for (int k0=0; k0<K; k0+=32){
    #pragma unroll
    for (int inst=0; inst<2; ++inst){
      int r = w*32 + inst*16 + arow;
      gload16(X + (size_t)(bm+r)*K + k0 + acol, &As[w*32+inst*16][0]);
    }
    #pragma unroll
    for (int it=0; it<2; ++it){
      const float* wp = W + (size_t)(bn+srow+it*64)*K + k0 + scol;
      float4 f0 = *(const float4*)(wp);
      float4 f1 = *(const float4*)(wp+4);
      uint4 bw;
      bw.x = (u32)f2bf(f0.x) | ((u32)f2bf(f0.y)<<16);
      bw.y = (u32)f2bf(f0.z) | ((u32)f2bf(f0.w)<<16);
      bw.z = (u32)f2bf(f1.x) | ((u32)f2bf(f1.y)<<16);
      bw.w = (u32)f2bf(f1.z) | ((u32)f2bf(f1.w)<<16);
      *(uint4*)&Bs[srow+it*64][scol] = bw;
    }
    __syncthreads();
    bf16x8 a[4], b[4];
    #pragma unroll
    for (int i=0;i<4;i++) a[i] = *(const bf16x8*)&As[wr+i*16+fr][g*8];
    #pragma unroll
    for (int i=0;i<4;i++) b[i] = *(const bf16x8*)&Bs[wc+i*16+fr][g*8];
    #pragma unroll
    for (int i=0;i<4;i++)
      #pragma unroll
      for (int j=0;j<4;j++)
        acc[i][j] = __builtin_amdgcn_mfma_f32_16x16x32_bf16(a[i], b[j], acc[i][j], 0, 0, 0);
    __syncthreads();
  }
  #pragma unroll
  for (int i=0;i<4;i++){
    #pragma unroll
    for (int j=0;j<4;j++){
      int col = bn + wc + j*16 + fr;
      float bv = bias ? bias[col] : 0.f;
      #pragma unroll
      for (int r=0;r<4;r++){
        int row = bm + wr + i*16 + g*4 + r;
        float y = acc[i][j][r] + bv;
        if (EPI == 0){
          Yout[(size_t)row*N + col] = f2bf(y);
        } else if (EPI == 1){
          Yout[(size_t)row*N + col] = f2bf(gelu_exact(y));
        } else if (EPI == 2){
          float gt = gate ? gate[col] : 1.f;
          resout[(size_t)row*N + col] = resin[(size_t)row*N + col] + gt*y;
        } else if (EPI == 3){
          Yout[(size_t)col*M + row] = f2bf(y);
        } else {
          Yout[(size_t)row*N + col] = f2bf(y*0.125f);
        }
      }
    }
  }
}

// ---------------- Flash attention (swapped QK^T, in-lane softmax) ----------------
// grid (Lq/64, H) xcd-swizzled; 4 waves x 16 q rows; KV tiles 64, dbuf prefetch.
// Q pre-scaled by 1/8. K: [L][1024]. VT: [1024][Lkv].
__global__ __launch_bounds__(256) void k_flash(
    const u16* __restrict__ Q, const u16* __restrict__ Kb, const u16* __restrict__ VT,
    u16* __restrict__ O, int Lkv)
{
  __shared__ __align__(16) u16 Ks[2*64*64];
  __shared__ __align__(16) u16 Vs[2*64*64];
  __shared__ __align__(16) u16 Ps[4][16][72];
  int bx = blockIdx.x, by = blockIdx.y;
  xcd_remap(bx, by);
  int h = by;
  int q0 = bx*64;
  int t = threadIdx.x, w = t>>6, lane = t&63;
  int fr = lane&15, g = lane>>4;
  const u16* qrow = Q + (size_t)(q0 + w*16 + fr)*1024 + h*64;
  bf16x8 aq0 = *(const bf16x8*)(qrow + g*8);
  bf16x8 aq1 = *(const bf16x8*)(qrow + 32 + g*8);
  f32x4 accO[4] = {};
  float m = -1e30f, l = 0.f;
  int slot = lane & 7, rop = lane >> 3;
  const u16* kbase = Kb + (size_t)h*64;
  const u16* vbase = VT + (size_t)h*64*Lkv;
  int nt = Lkv >> 6;
  // prologue stage tile 0
  {
    #pragma unroll
    for (int inst=0; inst<2; ++inst){
      int row = w*16 + inst*8 + rop;
      int ss = slot ^ (row & 7);
      gload16(kbase + (size_t)row*1024 + ss*8, Ks + (w*16+inst*8)*64);
      gload16(vbase + (size_t)row*Lkv + ss*8, Vs + (w*16+inst*8)*64);
    }
  }
  for (int tt=0; tt<nt; ++tt){
    __syncthreads();
    int cur = tt & 1;
    if (tt+1 < nt){
      int nb = cur ^ 1;
      int k0 = (tt+1) << 6;
      #pragma unroll
      for (int inst=0; inst<2; ++inst){
        int row = w*16 + inst*8 + rop;
        int ss = slot ^ (row & 7);
        gload16(kbase + (size_t)(k0+row)*1024 + ss*8, Ks + nb*4096 + (w*16+inst*8)*64);
        gload16(vbase + (size_t)row*Lkv + k0 + ss*8, Vs + nb*4096 + (w*16+inst*8)*64);
      }
    }
    const u16* kc = Ks + cur*4096;
    const u16* vc = Vs + cur*4096;
    // S^T = K.Q^T : lane holds S[kv=kb*16+g*4+r][q=fr]
    f32x4 st[4] = {};
    #pragma unroll
    for (int kb=0;kb<4;kb++){
      int rowK = kb*16 + fr;
      bf16x8 b0 = *(const bf16x8*)(kc + rowK*64 + ((g  ) ^ (rowK&7))*8);
      bf16x8 b1 = *(const bf16x8*)(kc + rowK*64 + ((4+g) ^ (rowK&7))*8);
      st[kb] = __builtin_amdgcn_mfma_f32_16x16x32_bf16(b0, aq0, st[kb], 0,0,0);
      st[kb] = __builtin_amdgcn_mfma_f32_16x16x32_bf16(b1, aq1, st[kb], 0,0,0);
    }
    // in-lane max over 16 values, then across the 4 lanes sharing q=fr
    float x[16];
    #pragma unroll
    for (int kb=0;kb<4;kb++)
      #pragma unroll
      for (int r=0;r<4;r++) x[kb*4+r] = st[kb][r];
    float tmax = x[0];
    #pragma unroll
    for (int ii=1; ii<16; ii++) tmax = fmaxf(tmax, x[ii]);
    tmax = fmaxf(tmax, __shfl_xor(tmax, 16));
    tmax = fmaxf(tmax, __shfl_xor(tmax, 32));
    if (!__all(tmax <= m + 8.f)){
      float mn = fmaxf(m, tmax);
      float er = __expf(m - mn);
      m = mn;
      l *= er;
      #pragma unroll
      for (int r=0;r<4;r++){
        float erq = __shfl(er, g*4+r);
        #pragma unroll
        for (int nd=0; nd<4; nd++) accO[nd][r] *= erq;
      }
    }
    float ts = 0.f;
    u32 pk[8];
    #pragma unroll
    for (int kb=0;kb<4;kb++){
      float p0 = __expf(x[kb*4+0] - m);
      float p1 = __expf(x[kb*4+1] - m);
      float p2 = __expf(x[kb*4+2] - m);
      float p3 = __expf(x[kb*4+3] - m);
      ts += (p0+p1)+(p2+p3);
      pk[kb*2]   = pack2(p0,p1);
      pk[kb*2+1] = pack2(p2,p3);
    }
    ts += __shfl_xor(ts, 16);
    ts += __shfl_xor(ts, 32);
    l += ts;
    #pragma unroll
    for (int kb=0;kb<4;kb++){
      uint2 pv; pv.x = pk[kb*2]; pv.y = pk[kb*2+1];
      *(uint2*)&Ps[w][fr][kb*16 + g*4] = pv;
    }
    bf16x8 ap0 = *(const bf16x8*)&Ps[w][fr][g*8];
    bf16x8 ap1 = *(const bf16x8*)&Ps[w][fr][32 + g*8];
    #pragma unroll
    for (int nd=0; nd<4; nd++){
      int rowV = nd*16 + fr;
      bf16x8 b0 = *(const bf16x8*)(vc + rowV*64 + ((g  ) ^ (rowV&7))*8);
      bf16x8 b1 = *(const bf16x8*)(vc + rowV*64 + ((4+g) ^ (rowV&7))*8);
      accO[nd] = __builtin_amdgcn_mfma_f32_16x16x32_bf16(ap0, b0, accO[nd], 0,0,0);
      accO[nd] = __builtin_amdgcn_mfma_f32_16x16x32_bf16(ap1, b1, accO[nd], 0,0,0);
    }
  }
  float rl = 1.f / l;
  #pragma unroll
  for (int r=0;r<4;r++){
    float rlq = __shfl(rl, g*4+r);
    int row = q0 + w*16 + g*4 + r;
    #pragma unroll
    for (int nd=0; nd<4; nd++)
      O[(size_t)row*1024 + h*64 + nd*16 + fr] = f2bf(accO[nd][r] * rlq);
  }
}

// ---------------- launch ----------------
extern "C" void kernel_launch(void* const* d_in, const int* in_sizes, int n_in,
                              void* d_out, int out_size, void* d_ws, size_t ws_size,
                              hipStream_t stream){
  const float* x_in = (const float*)d_in[0];
  const float* te   = (const float*)d_in[1];
  const float* ctx  = (const float*)d_in[2];
  const float* rope = (const float*)d_in[3];
  const float* adaW = (const float*)d_in[4];
  const float* adab = (const float*)d_in[5];
  const float* sqW  = (const float*)d_in[6];
  const float* skW  = (const float*)d_in[7];
  const float* svW  = (const float*)d_in[8];
  const float* soW  = (const float*)d_in[9];
  const float* sob  = (const float*)d_in[10];
  const float* cqW  = (const float*)d_in[11];
  const float* ckW  = (const float*)d_in[12];
  const float* cvW  = (const float*)d_in[13];
  const float* coW  = (const float*)d_in[14];
  const float* cob  = (const float*)d_in[15];
  const float* f1W  = (const float*)d_in[16];
  const float* f1b  = (const float*)d_in[17];
  const float* f2W  = (const float*)d_in[18];
  const float* f2b  = (const float*)d_in[19];
  float* x = (float*)d_out;

  char* p = (char*)d_ws;
  size_t used = 0;
  auto alloc = [&](size_t bytes){
    void* r = (void*)(p + used);
    used += (bytes + 255) & ~(size_t)255;
    return r;
  };
  u16* hx   = (u16*)alloc((size_t)3072*1024*2);
  u16* qb   = (u16*)alloc((size_t)3072*1024*2);
  u16* kb   = (u16*)alloc((size_t)3072*1024*2);
  u16* vt   = (u16*)alloc((size_t)1024*3072*2);
  u16* ob   = (u16*)alloc((size_t)3072*1024*2);
  u16* mid  = (u16*)alloc((size_t)3072*4096*2);
  u16* ctxb = (u16*)alloc((size_t)512*1024*2);
  float* mods = (float*)alloc((size_t)2*6144*4);
  size_t base_used = used;
  const size_t NW_SMALL = (size_t)2*1024*1024;
  const size_t NW_BIG   = (size_t)2*4096*1024;
  size_t wbytes = (8*NW_SMALL + 2*NW_BIG)*2;
  bool pre = (base_used + wbytes + 4096) <= ws_size;

  u16 *sqWb=nullptr,*skWb=nullptr,*svWb=nullptr,*soWb=nullptr,
      *cqWb=nullptr,*ckWb=nullptr,*cvWb=nullptr,*coWb=nullptr,
      *f1Wb=nullptr,*f2Wb=nullptr;
  if (pre){
    sqWb=(u16*)alloc(NW_SMALL*2); skWb=(u16*)alloc(NW_SMALL*2);
    svWb=(u16*)alloc(NW_SMALL*2); soWb=(u16*)alloc(NW_SMALL*2);
    cqWb=(u16*)alloc(NW_SMALL*2); ckWb=(u16*)alloc(NW_SMALL*2);
    cvWb=(u16*)alloc(NW_SMALL*2); coWb=(u16*)alloc(NW_SMALL*2);
    f1Wb=(u16*)alloc(NW_BIG*2);   f2Wb=(u16*)alloc(NW_BIG*2);
    auto CVT = [&](const float* s, u16* d, size_t n){
      k_cvt_bf16<<<(int)(n/1024), 256, 0, stream>>>(s, d, (int)(n/4));
    };
    CVT(sqW,sqWb,NW_SMALL); CVT(skW,skWb,NW_SMALL);
    CVT(svW,svWb,NW_SMALL); CVT(soW,soWb,NW_SMALL);
    CVT(cqW,cqWb,NW_SMALL); CVT(ckW,ckWb,NW_SMALL);
    CVT(cvW,cvWb,NW_SMALL); CVT(coW,coWb,NW_SMALL);
    CVT(f1W,f1Wb,NW_BIG);   CVT(f2W,f2Wb,NW_BIG);
  }

  k_copy_f32<<<3072, 256, 0, stream>>>(x_in, x, 786432);
  k_cvt_bf16<<<512, 256, 0, stream>>>(ctx, ctxb, 131072);
  k_ada<<<3072, 256, 0, stream>>>(te, adaW, adab, mods);

  for (int i=0; i<2; ++i){
    const float* mi = mods + (size_t)i*6144;
    size_t wo = (size_t)i*1024*1024;
    size_t wof = (size_t)i*4096*1024;
    // --- self attention ---
    k_ln_mod<<<3072,256,0,stream>>>(x, mi+0, mi+1024, hx);
    if (pre){
      k_qkv<0><<<dim3(24,24),256,0,stream>>>(hx, sqWb+wo, skWb+wo, svWb+wo, qb, kb, vt, 3072, 3072);
    } else {
      k_gemm_f32<0><<<dim3(24,8),256,0,stream>>>(hx, sqW+wo, nullptr, qb, nullptr,nullptr,nullptr, 3072,1024,1024);
      k_gemm_f32<0><<<dim3(24,8),256,0,stream>>>(hx, skW+wo, nullptr, kb, nullptr,nullptr,nullptr, 3072,1024,1024);
      k_gemm_f32<3><<<dim3(24,8),256,0,stream>>>(hx, svW+wo, nullptr, vt, nullptr,nullptr,nullptr, 3072,1024,1024);
    }
    k_rope<<<6144,256,0,stream>>>(qb, kb, rope);
    k_flash<<<dim3(48,16),256,0,stream>>>(qb, kb, vt, ob, 3072);
    if (pre)
      k_gemm_bf16<2><<<dim3(24,8),256,0,stream>>>(ob, soWb+wo, sob+(size_t)i*1024, nullptr, x, x, mi+2048, 3072,1024,1024);
    else
      k_gemm_f32<2><<<dim3(24,8),256,0,stream>>>(ob, soW+wo, sob+(size_t)i*1024, nullptr, x, x, mi+2048, 3072,1024,1024);
    // --- cross attention ---
    k_ln_mod<<<3072,256,0,stream>>>(x, nullptr, nullptr, hx);
    if (pre){
      k_gemm_bf16<4><<<dim3(24,8),256,0,stream>>>(hx, cqWb+wo, nullptr, qb, nullptr,nullptr,nullptr, 3072,1024,1024);
      k_qkv<1><<<dim3(4,16),256,0,stream>>>(ctxb, ckWb+wo, cvWb+wo, nullptr, kb, nullptr, vt, 512, 512);
    } else {
      k_gemm_f32<4><<<dim3(24,8),256,0,stream>>>(hx, cqW+wo, nullptr, qb, nullptr,nullptr,nullptr, 3072,1024,1024);
      k_gemm_f32<0><<<dim3(4,8),256,0,stream>>>(ctxb, ckW+wo, nullptr, kb, nullptr,nullptr,nullptr, 512,1024,1024);
      k_gemm_f32<3><<<dim3(4,8),256,0,stream>>>(ctxb, cvW+wo, nullptr, vt, nullptr,nullptr,nullptr, 512,1024,1024);
    }
    k_flash<<<dim3(48,16),256,0,stream>>>(qb, kb, vt, ob, 512);
    if (pre)
      k_gemm_bf16<2><<<dim3(24,8),256,0,stream>>>(ob, coWb+wo, cob+(size_t)i*1024, nullptr, x, x, nullptr, 3072,1024,1024);
    else
      k_gemm_f32<2><<<dim3(24,8),256,0,stream>>>(ob, coW+wo, cob+(size_t)i*1024, nullptr, x, x, nullptr, 3072,1024,1024);
    // --- MLP ---
    k_ln_mod<<<3072,256,0,stream>>>(x, mi+3072, mi+4096, hx);
    if (pre){
      k_gemm_bf16<1><<<dim3(24,32),256,0,stream>>>(hx, f1Wb+wof, f1b+(size_t)i*4096, mid, nullptr,nullptr,nullptr, 3072,4096,1024);
      k_gemm_bf16<2><<<dim3(24,8),256,0,stream>>>(mid, f2Wb+wof, f2b+(size_t)i*1024, nullptr, x, x, mi+5120, 3072,1024,4096);
    } else {
      k_gemm_f32<1><<<dim3(24,32),256,0,stream>>>(hx, f1W+wof, f1b+(size_t)i*4096, mid, nullptr,nullptr,nullptr, 3072,4096,1024);
      k_gemm_f32<2><<<dim3(24,8),256,0,stream>>>(mid, f2W+wof, f2b+(size_t)i*1024, nullptr, x, x, mi+5120, 3072,1024,4096);
    }
  }
}